// Round 2
// baseline (78.619 us; speedup 1.0000x reference)
//
#include <hip/hip_runtime.h>

#define B_ 2
#define C_ 256
#define HW_ 64
#define N_ 4096
#define K_SEL 1228   // int(4096*0.3)
#define MIP_ 16

__device__ __forceinline__ float sigm(float z) { return 1.0f / (1.0f + expf(-z)); }

// ---------------------------------------------------------------- k_pre
// One block per (b,c): row means -> xh, col means -> xw, total sum -> Tc.
__global__ __launch_bounds__(256) void k_pre(const float* __restrict__ x,
                                             float* __restrict__ xh,
                                             float* __restrict__ xw,
                                             float* __restrict__ Tc) {
  __shared__ float rp[64][17];   // row partial sums
  __shared__ float cp[16][65];   // col partial sums
  __shared__ float tb[64];
  int bc = blockIdx.x, t = threadIdx.x;
  const float* src = x + (size_t)bc * N_;
  int g = t >> 4;     // 0..15
  int b16 = t & 15;   // 0..15
  float c0 = 0, c1 = 0, c2 = 0, c3 = 0;
  #pragma unroll
  for (int it = 0; it < 4; ++it) {
    int row = it * 16 + g;
    float4 v = *(const float4*)&src[row * 64 + b16 * 4];
    rp[row][b16] = v.x + v.y + v.z + v.w;
    c0 += v.x; c1 += v.y; c2 += v.z; c3 += v.w;
  }
  cp[g][b16 * 4 + 0] = c0;
  cp[g][b16 * 4 + 1] = c1;
  cp[g][b16 * 4 + 2] = c2;
  cp[g][b16 * 4 + 3] = c3;
  __syncthreads();
  if (t < 64) {
    float rs = 0;
    #pragma unroll
    for (int i = 0; i < 16; ++i) rs += rp[t][i];
    xh[bc * 64 + t] = rs * (1.0f / 64.0f);
    tb[t] = rs;
    float cs = 0;
    #pragma unroll
    for (int gg = 0; gg < 16; ++gg) cs += cp[gg][t];
    xw[bc * 64 + t] = cs * (1.0f / 64.0f);
  }
  __syncthreads();
  if (t < 32) tb[t] += tb[t + 32];
  __syncthreads();
  if (t < 16) tb[t] += tb[t + 16];
  __syncthreads();
  if (t < 8) tb[t] += tb[t + 8];
  __syncthreads();
  if (t < 4) tb[t] += tb[t + 4];
  __syncthreads();
  if (t < 2) tb[t] += tb[t + 2];
  __syncthreads();
  if (t == 0) Tc[bc] = tb[0] + tb[1];
}

// ---------------------------------------------------------------- k_mid
// One block per batch: conv1+BN+ReLU on [x_h | x_w] (x_d1 == x_d2 == x_h),
// attention sigmoids, f, exact k-th-largest threshold (bit binary search),
// masked f (fs), q-moments, dinv[b,i] = 1/denom_i. All reductions via LDS.
__global__ __launch_bounds__(256) void k_mid(
    const float* __restrict__ xh, const float* __restrict__ xw,
    const float* __restrict__ w1, const float* __restrict__ b1,
    const float* __restrict__ gam, const float* __restrict__ bet,
    const float* __restrict__ mea, const float* __restrict__ var,
    const float* __restrict__ wh, const float* __restrict__ bh,
    const float* __restrict__ ww, const float* __restrict__ bw,
    const float* __restrict__ wd1, const float* __restrict__ bd1,
    const float* __restrict__ wd2, const float* __restrict__ bd2,
    const float* __restrict__ msk,
    float* __restrict__ f, float* __restrict__ fs, float* __restrict__ dinv) {
  __shared__ float sw1[MIP_ * C_];
  __shared__ float fh[MIP_][HW_];
  __shared__ float fw[MIP_][HW_];
  __shared__ float ah[HW_];
  __shared__ float sp[HW_];
  __shared__ unsigned fb[N_];
  __shared__ int ibuf[256];
  __shared__ float fbuf[256];
  __shared__ float qsh[8];
  int b = blockIdx.x, t = threadIdx.x;
  for (int i = t; i < MIP_ * C_; i += 256) sw1[i] = w1[i];
  __syncthreads();

  // conv1 over 256 input channels; threads 0..127: seg = t>>6 (0:h, 1:w)
  int pos = t & 63, seg = t >> 6;
  if (seg < 2) {
    const float* base = (seg == 0 ? xh : xw) + b * C_ * HW_;
    float acc[MIP_];
    #pragma unroll
    for (int o = 0; o < MIP_; ++o) acc[o] = 0.0f;
    for (int c = 0; c < C_; ++c) {
      float v = base[c * HW_ + pos];
      #pragma unroll
      for (int o = 0; o < MIP_; ++o) acc[o] = fmaf(sw1[o * C_ + c], v, acc[o]);
    }
    #pragma unroll
    for (int o = 0; o < MIP_; ++o) {
      float sc = gam[o] * rsqrtf(var[o] + 1e-5f);
      float y = acc[o] + b1[o] - mea[o];
      float r = fmaxf(fmaf(y, sc, bet[o]), 0.0f);
      if (seg == 0) fh[o][pos] = r; else fw[o][pos] = r;
    }
  }
  __syncthreads();

  // a_h from fh; a_w from fw; a_d1/a_d2 from fh
  if (t < HW_) {
    float aH = bh[0], aW = bw[0], aD1 = bd1[0], aD2 = bd2[0];
    #pragma unroll
    for (int o = 0; o < MIP_; ++o) {
      float vh = fh[o][t], vw = fw[o][t];
      aH = fmaf(wh[o], vh, aH);
      aW = fmaf(ww[o], vw, aW);
      aD1 = fmaf(wd1[o], vh, aD1);
      aD2 = fmaf(wd2[o], vh, aD2);
    }
    ah[t] = sigm(aH);
    sp[t] = sigm(aW) * sigm(aD1) * sigm(aD2);
  }
  __syncthreads();

  // f[j] = a_h[h] * (a_w*a_d1*a_d2)[w],  j = h*64 + w
  float* fg = f + b * N_;
  for (int j = t; j < N_; j += 256) {
    float v = ah[j >> 6] * sp[j & 63];
    fg[j] = v;
    fb[j] = __float_as_uint(v);   // positive floats order like uints
  }
  __syncthreads();

  // k-th largest via bit binary search; invariant cnt_ge(lo)>=K, cnt_ge(hi)<K
  unsigned lo = 0u, hi = 0x3f800000u;  // f in (0,1) strictly
  while (hi - lo > 1u) {
    unsigned mid = lo + ((hi - lo) >> 1);
    int cnt = 0;
    for (int j = t; j < N_; j += 256) cnt += (fb[j] >= mid) ? 1 : 0;
    ibuf[t] = cnt;
    __syncthreads();
    for (int off = 128; off; off >>= 1) {
      if (t < off) ibuf[t] += ibuf[t + off];
      __syncthreads();
    }
    int total = ibuf[0];
    __syncthreads();
    if (total >= K_SEL) lo = mid; else hi = mid;
  }
  unsigned tint = lo;

  // masked f + q-moments over selected set
  float qm[7] = {0, 0, 0, 0, 0, 0, 0};
  float* fsg = fs + b * N_;
  for (int j = t; j < N_; j += 256) {
    unsigned u = fb[j];
    float v = __uint_as_float(u);
    if (u >= tint) {
      fsg[j] = v;
      float p = v;
      #pragma unroll
      for (int m = 0; m < 7; ++m) { qm[m] += p; p *= v; }
    } else {
      fsg[j] = 0.0f;
    }
  }
  {
    const float invf[7] = {1.0f, 0.5f, 1.0f / 6.0f, 1.0f / 24.0f,
                           1.0f / 120.0f, 1.0f / 720.0f, 1.0f / 5040.0f};
    for (int m = 0; m < 7; ++m) {
      fbuf[t] = qm[m];
      __syncthreads();
      for (int off = 128; off; off >>= 1) {
        if (t < off) fbuf[t] += fbuf[t + off];
        __syncthreads();
      }
      if (t == 0) qsh[1 + m] = fbuf[0] * invf[m];
      __syncthreads();
    }
  }

  // dinv[b,i] = 1 / (N + sum_{m>=1} alpha^m q_m/m!),  alpha = g*f_i
  float gm = sigm(msk[0]);
  float q1 = qsh[1], q2 = qsh[2], q3 = qsh[3], q4 = qsh[4];
  float q5 = qsh[5], q6 = qsh[6], q7 = qsh[7];
  float* dg = dinv + b * N_;
  for (int j = t; j < N_; j += 256) {
    float alpha = gm * __uint_as_float(fb[j]);
    float h = q7;
    h = fmaf(alpha, h, q6);
    h = fmaf(alpha, h, q5);
    h = fmaf(alpha, h, q4);
    h = fmaf(alpha, h, q3);
    h = fmaf(alpha, h, q2);
    h = fmaf(alpha, h, q1);
    float denom = fmaf(alpha, h, (float)N_);
    dg[j] = 1.0f / denom;
  }
}

// ---------------------------------------------------------------- k_fin
// One block per (b,c): P_m = sum_{j in S} f_j^m x[c,j] / m! (m=1..7), then
// out[b,c,i] = (T + sum alpha^m P_m) * dinv[b,i]  — FLOAT32 store.
__global__ __launch_bounds__(256) void k_fin(const float* __restrict__ x,
                                             const float* __restrict__ fs,
                                             const float* __restrict__ Tc,
                                             const float* __restrict__ f,
                                             const float* __restrict__ dinv,
                                             const float* __restrict__ msk,
                                             float* __restrict__ out) {
  __shared__ float fbuf[256];
  __shared__ float ps[8];
  int bc = blockIdx.x;
  int b = bc >> 8;
  int t = threadIdx.x;
  const float* xr = x + (size_t)bc * N_;
  const float* fr = fs + (size_t)b * N_;
  float pm[7] = {0, 0, 0, 0, 0, 0, 0};
  #pragma unroll
  for (int it = 0; it < 4; ++it) {
    int j = it * 1024 + t * 4;
    float4 xv = *(const float4*)&xr[j];
    float4 fv = *(const float4*)&fr[j];
    const float xe[4] = {xv.x, xv.y, xv.z, xv.w};
    const float fe[4] = {fv.x, fv.y, fv.z, fv.w};
    #pragma unroll
    for (int e = 0; e < 4; ++e) {
      float xx = xe[e], v = fe[e];
      float p = v;
      #pragma unroll
      for (int m = 0; m < 7; ++m) { pm[m] = fmaf(p, xx, pm[m]); p *= v; }
    }
  }
  {
    const float invf[7] = {1.0f, 0.5f, 1.0f / 6.0f, 1.0f / 24.0f,
                           1.0f / 120.0f, 1.0f / 720.0f, 1.0f / 5040.0f};
    for (int m = 0; m < 7; ++m) {
      fbuf[t] = pm[m];
      __syncthreads();
      for (int off = 128; off; off >>= 1) {
        if (t < off) fbuf[t] += fbuf[t + off];
        __syncthreads();
      }
      if (t == 0) ps[1 + m] = fbuf[0] * invf[m];
      __syncthreads();
    }
  }
  float T = Tc[bc];
  float gm = sigm(msk[0]);
  float p1 = ps[1], p2 = ps[2], p3 = ps[3], p4 = ps[4];
  float p5 = ps[5], p6 = ps[6], p7 = ps[7];
  const float* fbp = f + (size_t)b * N_;
  const float* db = dinv + (size_t)b * N_;
  float* ob = out + (size_t)bc * N_;
  for (int it = 0; it < 16; ++it) {
    int i = it * 256 + t;
    float alpha = gm * fbp[i];
    float h = p7;
    h = fmaf(alpha, h, p6);
    h = fmaf(alpha, h, p5);
    h = fmaf(alpha, h, p4);
    h = fmaf(alpha, h, p3);
    h = fmaf(alpha, h, p2);
    h = fmaf(alpha, h, p1);
    float numer = fmaf(alpha, h, T);
    ob[i] = numer * db[i];
  }
}

extern "C" void kernel_launch(void* const* d_in, const int* in_sizes, int n_in,
                              void* d_out, int out_size, void* d_ws, size_t ws_size,
                              hipStream_t stream) {
  const float* x   = (const float*)d_in[0];
  const float* w1  = (const float*)d_in[1];
  const float* b1  = (const float*)d_in[2];
  const float* gam = (const float*)d_in[3];
  const float* bet = (const float*)d_in[4];
  const float* mea = (const float*)d_in[5];
  const float* var = (const float*)d_in[6];
  const float* wh  = (const float*)d_in[7];
  const float* bh  = (const float*)d_in[8];
  const float* ww  = (const float*)d_in[9];
  const float* bw  = (const float*)d_in[10];
  const float* wd1 = (const float*)d_in[11];
  const float* bd1 = (const float*)d_in[12];
  const float* wd2 = (const float*)d_in[13];
  const float* bd2 = (const float*)d_in[14];
  const float* msk = (const float*)d_in[15];
  float* out = (float*)d_out;

  float* ws = (float*)d_ws;
  float* xh = ws;                     // 32768 floats
  float* xw = xh + B_ * C_ * HW_;     // 32768
  float* Tc = xw + B_ * C_ * HW_;     // 512
  float* f  = Tc + B_ * C_;           // 8192
  float* fs = f + B_ * N_;            // 8192
  float* di = fs + B_ * N_;           // 8192

  hipLaunchKernelGGL(k_pre, dim3(B_ * C_), dim3(256), 0, stream, x, xh, xw, Tc);
  hipLaunchKernelGGL(k_mid, dim3(B_), dim3(256), 0, stream,
                     xh, xw, w1, b1, gam, bet, mea, var,
                     wh, bh, ww, bw, wd1, bd1, wd2, bd2, msk, f, fs, di);
  hipLaunchKernelGGL(k_fin, dim3(B_ * C_), dim3(256), 0, stream,
                     x, fs, Tc, f, di, msk, out);
}

// Round 3
// 53.395 us; speedup vs baseline: 1.4724x; 1.4724x over previous
//
#include <hip/hip_runtime.h>

#define B_ 2
#define C_ 256
#define HW_ 64
#define N_ 4096
#define K_SEL 1228   // int(4096*0.3)
#define MIP_ 16

__device__ __forceinline__ float sigm(float z) { return 1.0f / (1.0f + expf(-z)); }

// ---------------------------------------------------------------- k_pre
// One block per (b,c): row means and col means, stored TRANSPOSED:
// xhT[((b*2+seg)*64 + pos)*256 + c],  seg 0 = row-mean (x_h), 1 = col-mean (x_w)
__global__ __launch_bounds__(256) void k_pre(const float* __restrict__ x,
                                             float* __restrict__ xhT) {
  __shared__ float rp[64][17];
  __shared__ float cp[16][65];
  int bc = blockIdx.x, t = threadIdx.x;
  int b = bc >> 8, c = bc & 255;
  const float* src = x + (size_t)bc * N_;
  int g = t >> 4, b16 = t & 15;
  float c0 = 0, c1 = 0, c2 = 0, c3 = 0;
  #pragma unroll
  for (int it = 0; it < 4; ++it) {
    int row = it * 16 + g;
    float4 v = *(const float4*)&src[row * 64 + b16 * 4];
    rp[row][b16] = v.x + v.y + v.z + v.w;
    c0 += v.x; c1 += v.y; c2 += v.z; c3 += v.w;
  }
  cp[g][b16 * 4 + 0] = c0;
  cp[g][b16 * 4 + 1] = c1;
  cp[g][b16 * 4 + 2] = c2;
  cp[g][b16 * 4 + 3] = c3;
  __syncthreads();
  if (t < 64) {
    float rs = 0;
    #pragma unroll
    for (int i = 0; i < 16; ++i) rs += rp[t][i];
    xhT[(((b * 2 + 0) * 64 + t) << 8) + c] = rs * (1.0f / 64.0f);
    float cs = 0;
    #pragma unroll
    for (int gg = 0; gg < 16; ++gg) cs += cp[gg][t];
    xhT[(((b * 2 + 1) * 64 + t) << 8) + c] = cs * (1.0f / 64.0f);
  }
}

// ---------------------------------------------------------------- k_mid
// One block per batch. conv1+BN+ReLU (scalar-load weights, float4 activations),
// sigmoids, rank-1 f = ah x sp, barrier-free wave0 bit-bisection for the
// exact k-th largest, masked f (fs), q-moments, ad[i] = (alpha_i, 1/denom_i).
__global__ __launch_bounds__(256) void k_mid(
    const float* __restrict__ xhT,
    const float* __restrict__ w1, const float* __restrict__ b1,
    const float* __restrict__ gam, const float* __restrict__ bet,
    const float* __restrict__ mea, const float* __restrict__ var,
    const float* __restrict__ wh, const float* __restrict__ bh,
    const float* __restrict__ ww, const float* __restrict__ bw,
    const float* __restrict__ wd1, const float* __restrict__ bd1,
    const float* __restrict__ wd2, const float* __restrict__ bd2,
    const float* __restrict__ msk,
    float* __restrict__ fs, float2* __restrict__ ad) {
  __shared__ float convo[2][MIP_][HW_];
  __shared__ float ahs[HW_], sps[HW_];
  __shared__ unsigned tsh;
  __shared__ float qpart[7][4];
  __shared__ float qsh[7];
  int b = blockIdx.x, t = threadIdx.x;
  int og = __builtin_amdgcn_readfirstlane(t >> 7);        // wave-uniform
  int seg = __builtin_amdgcn_readfirstlane((t >> 6) & 1); // wave-uniform
  int pos = t & 63;

  // ---- conv1: acc[oo] = sum_c w1[og*8+oo][c] * Y[b][seg][pos][c]
  const float* yrow = xhT + (((b * 2 + seg) * 64 + pos) << 8);
  const float* wbase = w1 + og * 8 * C_;   // uniform pointer
  float acc[8] = {0, 0, 0, 0, 0, 0, 0, 0};
  #pragma unroll 4
  for (int c = 0; c < C_; c += 4) {
    float4 v = *(const float4*)&yrow[c];
    #pragma unroll
    for (int oo = 0; oo < 8; ++oo) {
      const float* wr = wbase + oo * C_ + c;   // uniform -> s_load
      acc[oo] = fmaf(wr[0], v.x, acc[oo]);
      acc[oo] = fmaf(wr[1], v.y, acc[oo]);
      acc[oo] = fmaf(wr[2], v.z, acc[oo]);
      acc[oo] = fmaf(wr[3], v.w, acc[oo]);
    }
  }
  #pragma unroll
  for (int oo = 0; oo < 8; ++oo) {
    int o = og * 8 + oo;
    float sc = gam[o] * rsqrtf(var[o] + 1e-5f);
    float y = acc[oo] + b1[o] - mea[o];
    convo[seg][o][pos] = fmaxf(fmaf(y, sc, bet[o]), 0.0f);
  }
  __syncthreads();

  // ---- attention sigmoids (wave 0): ah, sp
  float av = 0.0f, spv = 0.0f;
  if (t < 64) {
    float aH = bh[0], aW = bw[0], aD1 = bd1[0], aD2 = bd2[0];
    #pragma unroll
    for (int o = 0; o < MIP_; ++o) {
      float vh = convo[0][o][t], vw = convo[1][o][t];
      aH = fmaf(wh[o], vh, aH);
      aW = fmaf(ww[o], vw, aW);
      aD1 = fmaf(wd1[o], vh, aD1);
      aD2 = fmaf(wd2[o], vh, aD2);
    }
    av = sigm(aH);
    spv = sigm(aW) * sigm(aD1) * sigm(aD2);
    ahs[t] = av;
    sps[t] = spv;
  }
  __syncthreads();

  // ---- wave0: exact k-th largest of the 4096 products, barrier-free
  if (t < 64) {
    unsigned pb[64];
    #pragma unroll
    for (int w = 0; w < 64; ++w)
      pb[w] = __float_as_uint(av * __shfl(spv, w, 64));
    float amx = av, amn = av, smx = spv, smn = spv;
    #pragma unroll
    for (int o = 32; o; o >>= 1) {
      amx = fmaxf(amx, __shfl_xor(amx, o, 64));
      amn = fminf(amn, __shfl_xor(amn, o, 64));
      smx = fmaxf(smx, __shfl_xor(smx, o, 64));
      smn = fminf(smn, __shfl_xor(smn, o, 64));
    }
    unsigned lo = __float_as_uint(amn * smn);       // cnt_ge(lo) = 4096 >= K
    unsigned hi = __float_as_uint(amx * smx) + 1u;  // cnt_ge(hi) = 0 < K
    while (hi - lo > 1u) {
      unsigned mid = lo + ((hi - lo) >> 1);
      int cnt = 0;
      #pragma unroll
      for (int w = 0; w < 64; ++w) cnt += (pb[w] >= mid) ? 1 : 0;
      #pragma unroll
      for (int o = 32; o; o >>= 1) cnt += __shfl_xor(cnt, o, 64);
      if (cnt >= K_SEL) lo = mid; else hi = mid;
    }
    if (t == 0) tsh = lo;
  }
  __syncthreads();
  unsigned tint = tsh;
  float gm = sigm(msk[0]);

  // ---- fs + q-moments (all 256 threads, shfl reduce, one barrier)
  float qm[7] = {0, 0, 0, 0, 0, 0, 0};
  float* fsb = fs + b * N_;
  #pragma unroll
  for (int k = 0; k < 16; ++k) {
    int j = k * 256 + t;
    float v = ahs[j >> 6] * sps[j & 63];
    unsigned u = __float_as_uint(v);
    bool sel = u >= tint;
    fsb[j] = sel ? v : 0.0f;
    if (sel) {
      float p = v;
      qm[0] += p; p *= v;
      qm[1] += p; p *= v;
      qm[2] += p; p *= v;
      qm[3] += p; p *= v;
      qm[4] += p; p *= v;
      qm[5] += p; p *= v;
      qm[6] += p;
    }
  }
  #pragma unroll
  for (int m = 0; m < 7; ++m) {
    float s = qm[m];
    #pragma unroll
    for (int o = 32; o; o >>= 1) s += __shfl_xor(s, o, 64);
    if ((t & 63) == 0) qpart[m][t >> 6] = s;
  }
  __syncthreads();
  if (t < 7) {
    const float invf[7] = {1.0f, 0.5f, 1.0f / 6.0f, 1.0f / 24.0f,
                           1.0f / 120.0f, 1.0f / 720.0f, 1.0f / 5040.0f};
    qsh[t] = (qpart[t][0] + qpart[t][1] + qpart[t][2] + qpart[t][3]) * invf[t];
  }
  __syncthreads();

  // ---- ad[i] = (alpha_i, 1/denom_i)
  float q1 = qsh[0], q2 = qsh[1], q3 = qsh[2], q4 = qsh[3];
  float q5 = qsh[4], q6 = qsh[5], q7 = qsh[6];
  float2* adb = ad + b * N_;
  #pragma unroll
  for (int k = 0; k < 16; ++k) {
    int j = k * 256 + t;
    float alpha = gm * (ahs[j >> 6] * sps[j & 63]);
    float h = q7;
    h = fmaf(alpha, h, q6);
    h = fmaf(alpha, h, q5);
    h = fmaf(alpha, h, q4);
    h = fmaf(alpha, h, q3);
    h = fmaf(alpha, h, q2);
    h = fmaf(alpha, h, q1);
    float denom = fmaf(alpha, h, (float)N_);
    adb[j] = make_float2(alpha, 1.0f / denom);
  }
}

// ---------------------------------------------------------------- k_fin
// One block per (b,c): T = sum_j x; P_m = sum_{S} f^m x / m!; then
// out[b,c,i] = (T + alpha_i*(P1 + alpha_i*(...))) * dinv_i   (f32 store)
__global__ __launch_bounds__(256) void k_fin(const float* __restrict__ x,
                                             const float* __restrict__ fs,
                                             const float2* __restrict__ ad,
                                             float* __restrict__ out) {
  __shared__ float part[8][4];
  __shared__ float ps[8];
  int bc = blockIdx.x, b = bc >> 8, t = threadIdx.x;
  const float* xr = x + (size_t)bc * N_;
  const float* fr = fs + (size_t)b * N_;
  float pm[8] = {0, 0, 0, 0, 0, 0, 0, 0};
  #pragma unroll
  for (int it = 0; it < 4; ++it) {
    int j = it * 1024 + t * 4;
    float4 xv = *(const float4*)&xr[j];
    float4 fv = *(const float4*)&fr[j];
    const float xe[4] = {xv.x, xv.y, xv.z, xv.w};
    const float fe[4] = {fv.x, fv.y, fv.z, fv.w};
    #pragma unroll
    for (int e = 0; e < 4; ++e) {
      float xx = xe[e], v = fe[e];
      pm[0] += xx;
      float p = v;
      pm[1] = fmaf(p, xx, pm[1]); p *= v;
      pm[2] = fmaf(p, xx, pm[2]); p *= v;
      pm[3] = fmaf(p, xx, pm[3]); p *= v;
      pm[4] = fmaf(p, xx, pm[4]); p *= v;
      pm[5] = fmaf(p, xx, pm[5]); p *= v;
      pm[6] = fmaf(p, xx, pm[6]); p *= v;
      pm[7] = fmaf(p, xx, pm[7]);
    }
  }
  #pragma unroll
  for (int m = 0; m < 8; ++m) {
    float s = pm[m];
    #pragma unroll
    for (int o = 32; o; o >>= 1) s += __shfl_xor(s, o, 64);
    if ((t & 63) == 0) part[m][t >> 6] = s;
  }
  __syncthreads();
  if (t < 8) {
    const float invf[8] = {1.0f, 1.0f, 0.5f, 1.0f / 6.0f, 1.0f / 24.0f,
                           1.0f / 120.0f, 1.0f / 720.0f, 1.0f / 5040.0f};
    ps[t] = (part[t][0] + part[t][1] + part[t][2] + part[t][3]) * invf[t];
  }
  __syncthreads();
  float T = ps[0];
  float p1 = ps[1], p2 = ps[2], p3 = ps[3], p4 = ps[4];
  float p5 = ps[5], p6 = ps[6], p7 = ps[7];
  const float2* adb = ad + (size_t)b * N_;
  float* ob = out + (size_t)bc * N_;
  #pragma unroll 4
  for (int it = 0; it < 16; ++it) {
    int i = it * 256 + t;
    float2 a = adb[i];
    float h = p7;
    h = fmaf(a.x, h, p6);
    h = fmaf(a.x, h, p5);
    h = fmaf(a.x, h, p4);
    h = fmaf(a.x, h, p3);
    h = fmaf(a.x, h, p2);
    h = fmaf(a.x, h, p1);
    ob[i] = fmaf(a.x, h, T) * a.y;
  }
}

extern "C" void kernel_launch(void* const* d_in, const int* in_sizes, int n_in,
                              void* d_out, int out_size, void* d_ws, size_t ws_size,
                              hipStream_t stream) {
  (void)in_sizes; (void)n_in; (void)out_size; (void)ws_size;
  const float* x   = (const float*)d_in[0];
  const float* w1  = (const float*)d_in[1];
  const float* b1  = (const float*)d_in[2];
  const float* gam = (const float*)d_in[3];
  const float* bet = (const float*)d_in[4];
  const float* mea = (const float*)d_in[5];
  const float* var = (const float*)d_in[6];
  const float* wh  = (const float*)d_in[7];
  const float* bh  = (const float*)d_in[8];
  const float* ww  = (const float*)d_in[9];
  const float* bw  = (const float*)d_in[10];
  const float* wd1 = (const float*)d_in[11];
  const float* bd1 = (const float*)d_in[12];
  const float* wd2 = (const float*)d_in[13];
  const float* bd2 = (const float*)d_in[14];
  const float* msk = (const float*)d_in[15];
  float* out = (float*)d_out;

  float* ws = (float*)d_ws;
  float* xhT = ws;                       // 65536 floats
  float* fs  = ws + 65536;               // 8192
  float2* ad = (float2*)(ws + 65536 + 8192);  // 8192 float2

  hipLaunchKernelGGL(k_pre, dim3(B_ * C_), dim3(256), 0, stream, x, xhT);
  hipLaunchKernelGGL(k_mid, dim3(B_), dim3(256), 0, stream,
                     xhT, w1, b1, gam, bet, mea, var,
                     wh, bh, ww, bw, wd1, bd1, wd2, bd2, msk, fs, ad);
  hipLaunchKernelGGL(k_fin, dim3(B_ * C_), dim3(256), 0, stream,
                     x, fs, ad, out);
}

// Round 4
// 28.861 us; speedup vs baseline: 2.7240x; 1.8501x over previous
//
#include <hip/hip_runtime.h>

#define B_ 2
#define C_ 256
#define HW_ 64
#define N_ 4096
#define K_SEL 1228   // int(4096*0.3)
#define MIP_ 16

__device__ __forceinline__ float sigm(float z) { return 1.0f / (1.0f + expf(-z)); }

// ---------------------------------------------------------------- k_pre
// One block per (b,c): row means and col means, stored TRANSPOSED:
// xhT[((b*2+seg)*64 + pos)*256 + c],  seg 0 = row-mean (x_h), 1 = col-mean (x_w)
__global__ __launch_bounds__(256) void k_pre(const float* __restrict__ x,
                                             float* __restrict__ xhT) {
  __shared__ float rp[64][17];
  __shared__ float cp[16][65];
  int bc = blockIdx.x, t = threadIdx.x;
  int b = bc >> 8, c = bc & 255;
  const float* src = x + (size_t)bc * N_;
  int g = t >> 4, b16 = t & 15;
  float c0 = 0, c1 = 0, c2 = 0, c3 = 0;
  #pragma unroll
  for (int it = 0; it < 4; ++it) {
    int row = it * 16 + g;
    float4 v = *(const float4*)&src[row * 64 + b16 * 4];
    rp[row][b16] = v.x + v.y + v.z + v.w;
    c0 += v.x; c1 += v.y; c2 += v.z; c3 += v.w;
  }
  cp[g][b16 * 4 + 0] = c0;
  cp[g][b16 * 4 + 1] = c1;
  cp[g][b16 * 4 + 2] = c2;
  cp[g][b16 * 4 + 3] = c3;
  __syncthreads();
  if (t < 64) {
    float rs = 0;
    #pragma unroll
    for (int i = 0; i < 16; ++i) rs += rp[t][i];
    xhT[(((b * 2 + 0) * 64 + t) << 8) + c] = rs * (1.0f / 64.0f);
    float cs = 0;
    #pragma unroll
    for (int gg = 0; gg < 16; ++gg) cs += cp[gg][t];
    xhT[(((b * 2 + 1) * 64 + t) << 8) + c] = cs * (1.0f / 64.0f);
  }
}

// ---------------------------------------------------------------- k_conv
// One block (1 wave) per (b,seg,pos) row: 16-output 256-long conv via wave
// reduction, BN+ReLU, attention dots + sigmoids. Writes ah / sw / sd.
__global__ __launch_bounds__(64) void k_conv(
    const float* __restrict__ xhT,
    const float* __restrict__ w1, const float* __restrict__ b1,
    const float* __restrict__ gam, const float* __restrict__ bet,
    const float* __restrict__ mea, const float* __restrict__ var,
    const float* __restrict__ wh, const float* __restrict__ bh,
    const float* __restrict__ ww, const float* __restrict__ bw,
    const float* __restrict__ wd1, const float* __restrict__ bd1,
    const float* __restrict__ wd2, const float* __restrict__ bd2,
    float* __restrict__ ahb, float* __restrict__ swb, float* __restrict__ sdb) {
  int blk = blockIdx.x;            // (b*2+seg)*64 + pos
  int l = threadIdx.x;             // 0..63
  const float* yrow = xhT + ((size_t)blk << 8);
  float4 v = *(const float4*)&yrow[l * 4];
  float r[MIP_];
  #pragma unroll
  for (int o = 0; o < MIP_; ++o) {
    float4 wv = *(const float4*)&w1[o * C_ + l * 4];
    float p = fmaf(v.x, wv.x, fmaf(v.y, wv.y, fmaf(v.z, wv.z, v.w * wv.w)));
    #pragma unroll
    for (int off = 32; off; off >>= 1) p += __shfl_xor(p, off, 64);
    r[o] = p;   // full sum, present in all lanes
  }
  float aH = bh[0], aW = bw[0], aD1 = bd1[0], aD2 = bd2[0];
  #pragma unroll
  for (int o = 0; o < MIP_; ++o) {
    float sc = gam[o] * rsqrtf(var[o] + 1e-5f);
    float y = r[o] + b1[o] - mea[o];
    float rr = fmaxf(fmaf(y, sc, bet[o]), 0.0f);
    aH = fmaf(wh[o], rr, aH);
    aW = fmaf(ww[o], rr, aW);
    aD1 = fmaf(wd1[o], rr, aD1);
    aD2 = fmaf(wd2[o], rr, aD2);
  }
  if (l == 0) {
    int seg = (blk >> 6) & 1, b = blk >> 7, pos = blk & 63;
    if (seg == 0) {
      ahb[b * HW_ + pos] = sigm(aH);
      sdb[b * HW_ + pos] = sigm(aD1) * sigm(aD2);
    } else {
      swb[b * HW_ + pos] = sigm(aW);
    }
  }
}

// ---------------------------------------------------------------- k_sel
// One block per batch. 4096 products held 16/lane in registers. Distributed
// bit-bisection (early stop at 8192-ULP slop), fs, q-moments, ad=(alpha,1/den).
__global__ __launch_bounds__(256) void k_sel(
    const float* __restrict__ ahb, const float* __restrict__ swb,
    const float* __restrict__ sdb, const float* __restrict__ msk,
    float* __restrict__ fs, float2* __restrict__ ad) {
  __shared__ float ahs[HW_], sps[HW_];
  __shared__ int icomb[4];
  __shared__ float fmn[4], fmx[4];
  __shared__ float qpart[7][4];
  __shared__ float qsh[7];
  int b = blockIdx.x, t = threadIdx.x;
  if (t < HW_) {
    ahs[t] = ahb[b * HW_ + t];
    sps[t] = swb[b * HW_ + t] * sdb[b * HW_ + t];
  }
  __syncthreads();

  // 16 products per thread, strided j = k*256 + t (coalesced stores later)
  float v[16];
  #pragma unroll
  for (int k = 0; k < 16; ++k) {
    int j = k * 256 + t;
    v[k] = ahs[j >> 6] * sps[j & 63];
  }

  // global min / max (positive floats: float order == bit order)
  float mn = v[0], mx = v[0];
  #pragma unroll
  for (int k = 1; k < 16; ++k) { mn = fminf(mn, v[k]); mx = fmaxf(mx, v[k]); }
  #pragma unroll
  for (int o = 32; o; o >>= 1) {
    mn = fminf(mn, __shfl_xor(mn, o, 64));
    mx = fmaxf(mx, __shfl_xor(mx, o, 64));
  }
  if ((t & 63) == 0) { fmn[t >> 6] = mn; fmx[t >> 6] = mx; }
  __syncthreads();
  mn = fminf(fminf(fmn[0], fmn[1]), fminf(fmn[2], fmn[3]));
  mx = fmaxf(fmaxf(fmx[0], fmx[1]), fmaxf(fmx[2], fmx[3]));
  __syncthreads();

  unsigned lo = __float_as_uint(mn);        // cnt_ge(lo) = 4096 >= K
  unsigned hi = __float_as_uint(mx) + 1u;   // cnt_ge(hi) = 0 < K
  while (hi - lo > 8192u) {
    unsigned mid = lo + ((hi - lo) >> 1);
    float midf = __uint_as_float(mid);
    int cnt = 0;
    #pragma unroll
    for (int k = 0; k < 16; ++k) cnt += (v[k] >= midf) ? 1 : 0;
    #pragma unroll
    for (int o = 32; o; o >>= 1) cnt += __shfl_xor(cnt, o, 64);
    if ((t & 63) == 0) icomb[t >> 6] = cnt;
    __syncthreads();
    int total = icomb[0] + icomb[1] + icomb[2] + icomb[3];
    __syncthreads();
    if (total >= K_SEL) lo = mid; else hi = mid;
  }
  float thr = __uint_as_float(lo);
  float gm = sigm(msk[0]);

  // fs + q-moments
  float qm[7] = {0, 0, 0, 0, 0, 0, 0};
  float* fsb = fs + b * N_;
  #pragma unroll
  for (int k = 0; k < 16; ++k) {
    int j = k * 256 + t;
    float vv = v[k];
    bool sel = vv >= thr;
    fsb[j] = sel ? vv : 0.0f;
    if (sel) {
      float p = vv;
      qm[0] += p; p *= vv;
      qm[1] += p; p *= vv;
      qm[2] += p; p *= vv;
      qm[3] += p; p *= vv;
      qm[4] += p; p *= vv;
      qm[5] += p; p *= vv;
      qm[6] += p;
    }
  }
  #pragma unroll
  for (int m = 0; m < 7; ++m) {
    float s = qm[m];
    #pragma unroll
    for (int o = 32; o; o >>= 1) s += __shfl_xor(s, o, 64);
    if ((t & 63) == 0) qpart[m][t >> 6] = s;
  }
  __syncthreads();
  if (t < 7) {
    const float invf[7] = {1.0f, 0.5f, 1.0f / 6.0f, 1.0f / 24.0f,
                           1.0f / 120.0f, 1.0f / 720.0f, 1.0f / 5040.0f};
    qsh[t] = (qpart[t][0] + qpart[t][1] + qpart[t][2] + qpart[t][3]) * invf[t];
  }
  __syncthreads();

  float q1 = qsh[0], q2 = qsh[1], q3 = qsh[2], q4 = qsh[3];
  float q5 = qsh[4], q6 = qsh[5], q7 = qsh[6];
  float2* adb = ad + b * N_;
  #pragma unroll
  for (int k = 0; k < 16; ++k) {
    int j = k * 256 + t;
    float alpha = gm * v[k];
    float h = q7;
    h = fmaf(alpha, h, q6);
    h = fmaf(alpha, h, q5);
    h = fmaf(alpha, h, q4);
    h = fmaf(alpha, h, q3);
    h = fmaf(alpha, h, q2);
    h = fmaf(alpha, h, q1);
    float denom = fmaf(alpha, h, (float)N_);
    adb[j] = make_float2(alpha, 1.0f / denom);
  }
}

// ---------------------------------------------------------------- k_fin
// One block per (b,c): T = sum_j x; P_m = sum_{S} f^m x / m!; then
// out[b,c,i] = (T + alpha_i*(P1 + alpha_i*(...))) * dinv_i   (f32 store)
__global__ __launch_bounds__(256) void k_fin(const float* __restrict__ x,
                                             const float* __restrict__ fs,
                                             const float2* __restrict__ ad,
                                             float* __restrict__ out) {
  __shared__ float part[8][4];
  __shared__ float ps[8];
  int bc = blockIdx.x, b = bc >> 8, t = threadIdx.x;
  const float* xr = x + (size_t)bc * N_;
  const float* fr = fs + (size_t)b * N_;
  float pm[8] = {0, 0, 0, 0, 0, 0, 0, 0};
  #pragma unroll
  for (int it = 0; it < 4; ++it) {
    int j = it * 1024 + t * 4;
    float4 xv = *(const float4*)&xr[j];
    float4 fv = *(const float4*)&fr[j];
    const float xe[4] = {xv.x, xv.y, xv.z, xv.w};
    const float fe[4] = {fv.x, fv.y, fv.z, fv.w};
    #pragma unroll
    for (int e = 0; e < 4; ++e) {
      float xx = xe[e], vv = fe[e];
      pm[0] += xx;
      float p = vv;
      pm[1] = fmaf(p, xx, pm[1]); p *= vv;
      pm[2] = fmaf(p, xx, pm[2]); p *= vv;
      pm[3] = fmaf(p, xx, pm[3]); p *= vv;
      pm[4] = fmaf(p, xx, pm[4]); p *= vv;
      pm[5] = fmaf(p, xx, pm[5]); p *= vv;
      pm[6] = fmaf(p, xx, pm[6]); p *= vv;
      pm[7] = fmaf(p, xx, pm[7]);
    }
  }
  #pragma unroll
  for (int m = 0; m < 8; ++m) {
    float s = pm[m];
    #pragma unroll
    for (int o = 32; o; o >>= 1) s += __shfl_xor(s, o, 64);
    if ((t & 63) == 0) part[m][t >> 6] = s;
  }
  __syncthreads();
  if (t < 8) {
    const float invf[8] = {1.0f, 1.0f, 0.5f, 1.0f / 6.0f, 1.0f / 24.0f,
                           1.0f / 120.0f, 1.0f / 720.0f, 1.0f / 5040.0f};
    ps[t] = (part[t][0] + part[t][1] + part[t][2] + part[t][3]) * invf[t];
  }
  __syncthreads();
  float T = ps[0];
  float p1 = ps[1], p2 = ps[2], p3 = ps[3], p4 = ps[4];
  float p5 = ps[5], p6 = ps[6], p7 = ps[7];
  const float2* adb = ad + (size_t)b * N_;
  float* ob = out + (size_t)bc * N_;
  #pragma unroll 4
  for (int it = 0; it < 16; ++it) {
    int i = it * 256 + t;
    float2 a = adb[i];
    float h = p7;
    h = fmaf(a.x, h, p6);
    h = fmaf(a.x, h, p5);
    h = fmaf(a.x, h, p4);
    h = fmaf(a.x, h, p3);
    h = fmaf(a.x, h, p2);
    h = fmaf(a.x, h, p1);
    ob[i] = fmaf(a.x, h, T) * a.y;
  }
}

extern "C" void kernel_launch(void* const* d_in, const int* in_sizes, int n_in,
                              void* d_out, int out_size, void* d_ws, size_t ws_size,
                              hipStream_t stream) {
  (void)in_sizes; (void)n_in; (void)out_size; (void)ws_size;
  const float* x   = (const float*)d_in[0];
  const float* w1  = (const float*)d_in[1];
  const float* b1  = (const float*)d_in[2];
  const float* gam = (const float*)d_in[3];
  const float* bet = (const float*)d_in[4];
  const float* mea = (const float*)d_in[5];
  const float* var = (const float*)d_in[6];
  const float* wh  = (const float*)d_in[7];
  const float* bh  = (const float*)d_in[8];
  const float* ww  = (const float*)d_in[9];
  const float* bw  = (const float*)d_in[10];
  const float* wd1 = (const float*)d_in[11];
  const float* bd1 = (const float*)d_in[12];
  const float* wd2 = (const float*)d_in[13];
  const float* bd2 = (const float*)d_in[14];
  const float* msk = (const float*)d_in[15];
  float* out = (float*)d_out;

  float* ws  = (float*)d_ws;
  float* xhT = ws;                        // 65536 floats
  float* ahb = ws + 65536;                // 128
  float* swb = ahb + 128;                 // 128
  float* sdb = swb + 128;                 // 128
  float* fs  = sdb + 128;                 // 8192
  float2* ad = (float2*)(fs + 8192);      // 8192 float2 (offset 74112 floats, 8B-aligned)

  hipLaunchKernelGGL(k_pre, dim3(B_ * C_), dim3(256), 0, stream, x, xhT);
  hipLaunchKernelGGL(k_conv, dim3(B_ * 2 * HW_), dim3(64), 0, stream,
                     xhT, w1, b1, gam, bet, mea, var,
                     wh, bh, ww, bw, wd1, bd1, wd2, bd2, ahb, swb, sdb);
  hipLaunchKernelGGL(k_sel, dim3(B_), dim3(256), 0, stream,
                     ahb, swb, sdb, msk, fs, ad);
  hipLaunchKernelGGL(k_fin, dim3(B_ * C_), dim3(256), 0, stream,
                     x, fs, ad, out);
}